// Round 6
// baseline (24139.297 us; speedup 1.0000x reference)
//
#include <hip/hip_runtime.h>
#include <math.h>

#define NN 512
#define DD 8192

// ---------------- row-norm scales: scale[m][r] = 1 / max(||row||, 1e-6) ----------------
__global__ __launch_bounds__(256) void norm_kernel(
    const float* __restrict__ a0, const float* __restrict__ a1,
    const float* __restrict__ a2, float* __restrict__ scales) {
  const float* mats[3] = {a0, a1, a2};
  const int m = blockIdx.y;
  const int row = blockIdx.x;
  const float* x = mats[m] + (size_t)row * DD;
  const int tid = threadIdx.x;
  float s = 0.f;
  for (int k = tid * 4; k < DD; k += 256 * 4) {
    const float4 v = *(const float4*)(x + k);
    s += v.x * v.x + v.y * v.y + v.z * v.z + v.w * v.w;
  }
#pragma unroll
  for (int off = 32; off > 0; off >>= 1) s += __shfl_down(s, off);
  __shared__ float ws[4];
  if ((tid & 63) == 0) ws[tid >> 6] = s;
  __syncthreads();
  if (tid == 0) {
    const float t = ws[0] + ws[1] + ws[2] + ws[3];
    scales[m * NN + row] = 1.0f / fmaxf(sqrtf(t), 1e-6f);
  }
}

// ---------------- cost_p = 1 - (A B^T) * sa * sb, p: (0:1->2, 1:2->3, 2:3->1) ----------
__global__ __launch_bounds__(256) void cost_gemm_kernel(
    const float* __restrict__ a0, const float* __restrict__ a1,
    const float* __restrict__ a2, const float* __restrict__ scales,
    float* __restrict__ cost_all) {
  const float* mats[3] = {a0, a1, a2};
  const int p = blockIdx.z;
  const int pA = p, pB = (p + 1) % 3;
  const float* A = mats[pA];
  const float* B = mats[pB];
  float* C = cost_all + (size_t)p * NN * NN;

  __shared__ float lds_a[32 * 64];
  __shared__ float lds_b[32 * 64];

  const int tid = threadIdx.x;
  const int rowBase = blockIdx.y * 64;
  const int colBase = blockIdx.x * 64;

  const int lr = tid & 63;   // row within tile for staging
  const int lq = tid >> 6;   // 0..3

  const float* Arow = A + (size_t)(rowBase + lr) * DD;
  const float* Brow = B + (size_t)(colBase + lr) * DD;

  float acc[4][4];
#pragma unroll
  for (int i = 0; i < 4; ++i)
#pragma unroll
    for (int j = 0; j < 4; ++j) acc[i][j] = 0.f;

  const int tx = tid & 15, ty = tid >> 4;

  for (int kb = 0; kb < DD; kb += 32) {
#pragma unroll
    for (int qq = 0; qq < 2; ++qq) {
      const int q = lq + qq * 4;  // 0..7, covers k offsets q*4..q*4+3
      const float4 av = *(const float4*)(Arow + kb + q * 4);
      const float4 bv = *(const float4*)(Brow + kb + q * 4);
      lds_a[(q * 4 + 0) * 64 + lr] = av.x;
      lds_a[(q * 4 + 1) * 64 + lr] = av.y;
      lds_a[(q * 4 + 2) * 64 + lr] = av.z;
      lds_a[(q * 4 + 3) * 64 + lr] = av.w;
      lds_b[(q * 4 + 0) * 64 + lr] = bv.x;
      lds_b[(q * 4 + 1) * 64 + lr] = bv.y;
      lds_b[(q * 4 + 2) * 64 + lr] = bv.z;
      lds_b[(q * 4 + 3) * 64 + lr] = bv.w;
    }
    __syncthreads();
#pragma unroll
    for (int k = 0; k < 32; ++k) {
      const float4 a4 = *(const float4*)(&lds_a[k * 64 + ty * 4]);
      const float4 b4 = *(const float4*)(&lds_b[k * 64 + tx * 4]);
      const float as0[4] = {a4.x, a4.y, a4.z, a4.w};
      const float bs0[4] = {b4.x, b4.y, b4.z, b4.w};
#pragma unroll
      for (int ii = 0; ii < 4; ++ii)
#pragma unroll
        for (int jj = 0; jj < 4; ++jj)
          acc[ii][jj] = fmaf(as0[ii], bs0[jj], acc[ii][jj]);
    }
    __syncthreads();
  }

#pragma unroll
  for (int ii = 0; ii < 4; ++ii) {
    const int gr = rowBase + ty * 4 + ii;
    const float sa = scales[pA * NN + gr];
#pragma unroll
    for (int jj = 0; jj < 4; ++jj) {
      const int gc = colBase + tx * 4 + jj;
      const float sb = scales[pB * NN + gc];
      C[gr * NN + gc] = 1.0f - acc[ii][jj] * sa * sb;
    }
  }
}

// ---------------- exact JV LAP with lapjv-style initialization, 1 wave / problem --------
// Lane owns columns j = lane*8+q (q=0..7). All cross-lane in-loop traffic via shfl;
// LDS handoffs fenced with __syncthreads (compiler fence — R2 lesson).
// R4 lesson: butterfly merges must be tie-consistent across lanes (lex (value,index)).
// R5 lesson: lapjv leaves rowsol of BUMPED rows stale (its SAP uses the free list);
// our SAP scans col4row — so bumped rows MUST have col4row cleared to -1, else they
// are skipped and the matching ends corrupt.

struct Min2 { double m1, m2; int j1, j2; };

__device__ __forceinline__ bool lex_less(double a, int ja, double b, int jb) {
  return a < b || (a == b && ja < jb);
}

__device__ __forceinline__ Min2 row_scan2(const float* __restrict__ rowp,
                                          const double* v, int lane) {
  const float4 c0 = *(const float4*)(rowp + lane * 8);
  const float4 c1 = *(const float4*)(rowp + lane * 8 + 4);
  const float cf[8] = {c0.x, c0.y, c0.z, c0.w, c1.x, c1.y, c1.z, c1.w};
  const double INF = __builtin_inf();
  double m1 = INF, m2 = INF;
  int j1 = 0x7fffffff, j2 = 0x7fffffff;
#pragma unroll
  for (int q = 0; q < 8; ++q) {
    const double h = (double)cf[q] - v[q];
    const int j = lane * 8 + q;
    if (h < m1) { m2 = m1; j2 = j1; m1 = h; j1 = j; }       // ascending j: tie keeps smaller
    else if (h < m2) { m2 = h; j2 = j; }
  }
#pragma unroll
  for (int off = 1; off < 64; off <<= 1) {
    const double o1 = __shfl_xor(m1, off);
    const double o2 = __shfl_xor(m2, off);
    const int oj1 = __shfl_xor(j1, off);
    const int oj2 = __shfl_xor(j2, off);
    if (lex_less(o1, oj1, m1, j1)) {
      if (lex_less(o2, oj2, m1, j1)) { m1 = o1; j1 = oj1; m2 = o2; j2 = oj2; }
      else { m2 = m1; j2 = j1; m1 = o1; j1 = oj1; }
    } else {
      if (lex_less(o1, oj1, m2, j2)) { m2 = o1; j2 = oj1; }
    }
  }
  // force wave-uniform result
  m1 = __shfl(m1, 0); j1 = __shfl(j1, 0);
  m2 = __shfl(m2, 0); j2 = __shfl(j2, 0);
  Min2 r; r.m1 = m1; r.m2 = m2; r.j1 = j1; r.j2 = j2;
  return r;
}

__global__ __launch_bounds__(64) void lap_kernel(
    const float* __restrict__ cost_all, float* __restrict__ out) {
  const int p = blockIdx.x;
  const float* __restrict__ cost = cost_all + (size_t)p * NN * NN;
  float* __restrict__ outp = out + (size_t)p * NN * NN;
  const int lane = threadIdx.x;  // 0..63

  __shared__ double sh_u[NN];
  __shared__ double sh_enter[NN];
  __shared__ int sh_path[NN];      // permuted: slot(j) = (j&7)*64 + (j>>3)
  __shared__ int sh_col4row[NN];
  __shared__ int sh_row4col[NN];
  __shared__ int sh_SRlist[NN];
  __shared__ int sh_free[NN];
  __shared__ int sh_cminrow[NN];
  __shared__ int sh_matches[NN];

  const double INF = __builtin_inf();
  double v[8];

#pragma unroll
  for (int q = 0; q < 8; ++q) {
    const int j = q * 64 + lane;
    sh_u[j] = 0.0;
    sh_col4row[j] = -1;
    sh_row4col[j] = -1;
    sh_matches[j] = 0;
  }
  __syncthreads();

  // ---- 1. column reduction: v[j] = min_i c[i][j], remember argmin row ----
  {
    float cmin[8];
    int cmr[8];
    const float4 c0 = *(const float4*)(cost + lane * 8);
    const float4 c1 = *(const float4*)(cost + lane * 8 + 4);
    const float f0[8] = {c0.x, c0.y, c0.z, c0.w, c1.x, c1.y, c1.z, c1.w};
#pragma unroll
    for (int q = 0; q < 8; ++q) { cmin[q] = f0[q]; cmr[q] = 0; }
    for (int i = 1; i < NN; ++i) {
      const float4 d0 = *(const float4*)(cost + i * NN + lane * 8);
      const float4 d1 = *(const float4*)(cost + i * NN + lane * 8 + 4);
      const float df[8] = {d0.x, d0.y, d0.z, d0.w, d1.x, d1.y, d1.z, d1.w};
#pragma unroll
      for (int q = 0; q < 8; ++q)
        if (df[q] < cmin[q]) { cmin[q] = df[q]; cmr[q] = i; }
    }
#pragma unroll
    for (int q = 0; q < 8; ++q) {
      v[q] = (double)cmin[q];
      sh_cminrow[lane * 8 + q] = cmr[q];
    }
  }
  __syncthreads();
  if (lane == 0) {
    for (int j = NN - 1; j >= 0; --j) {   // lapjv scan order
      const int r = sh_cminrow[j];
      const int m = sh_matches[r] + 1;
      sh_matches[r] = m;
      if (m == 1) { sh_col4row[r] = j; sh_row4col[j] = r; }
    }
  }
  __syncthreads();

  // ---- 2. reduction transfer for rows matched exactly once ----
  for (int i = 0; i < NN; ++i) {
    if (sh_matches[i] != 1) continue;          // uniform broadcast read
    const int j1 = sh_col4row[i];
    const Min2 s = row_scan2(cost + i * NN, v, lane);
    const double m = (s.j1 == j1) ? s.m2 : s.m1;  // min over j != j1
    if (lane == (j1 >> 3)) v[j1 & 7] -= m;
    if (lane == 0) sh_u[i] = m;                // new equality value
  }
  __syncthreads();

  // ---- free-row list (uniform: all lanes run identical read-only loop) ----
  int nf = 0;
  for (int i = 0; i < NN; ++i) {
    if (sh_col4row[i] < 0) {
      if (lane == 0) sh_free[nf] = i;
      nf++;
    }
  }
  __syncthreads();

  // ---- 3. augmenting row reduction, two passes (lapjv semantics) ----
  for (int pass = 0; pass < 2; ++pass) {
    const int prv = nf;
    nf = 0;
    int k = 0;
    int guard = NN * 64;
    while (k < prv && guard-- > 0) {
      const int i = sh_free[k]; k++;
      const Min2 s = row_scan2(cost + i * NN, v, lane);
      int jj = s.j1;
      int i0 = sh_row4col[jj];
      const bool strict = (s.m1 < s.m2);
      if (strict) {
        if (lane == (jj >> 3)) v[jj & 7] -= (s.m2 - s.m1);
      } else if (i0 >= 0) {
        jj = s.j2;
        i0 = sh_row4col[jj];
      }
      if (lane == 0) {
        sh_col4row[i] = jj;
        sh_row4col[jj] = i;
        sh_u[i] = s.m2;                        // equality value in all branches
        if (i0 >= 0) {
          sh_col4row[i0] = -1;                 // R5 fix: bumped row is now FREE
          if (strict) sh_free[k - 1] = i0;     // bumped row processed next
          else sh_free[nf] = i0;               // deferred to next pass
        }
      }
      if (i0 >= 0) { if (strict) k -= 1; else nf += 1; }
      __syncthreads();
    }
  }
  __syncthreads();

  // ---- 4. shortest augmenting path for remaining free rows ----
  double shortest[8];
  int rc[8];
#pragma unroll
  for (int q = 0; q < 8; ++q) rc[q] = sh_row4col[lane * 8 + q];

  for (int cur_row = 0; cur_row < NN; ++cur_row) {
    if (sh_col4row[cur_row] >= 0) continue;    // uniform broadcast read
    int scMask = 0;
#pragma unroll
    for (int q = 0; q < 8; ++q) shortest[q] = INF;

    int i = cur_row;
    double minv = 0.0;
    int nSR = 0;
    int sink = -1;

    while (true) {
      const double u_i = (i == cur_row) ? 0.0 : sh_u[i];
      const float* rp = cost + i * NN + lane * 8;
      const float4 c0 = *(const float4*)(rp);
      const float4 c1 = *(const float4*)(rp + 4);
      const float cf[8] = {c0.x, c0.y, c0.z, c0.w, c1.x, c1.y, c1.z, c1.w};

      double best = INF;
      int bj = 0x7fffffff;
      int brow = -1;
#pragma unroll
      for (int q = 0; q < 8; ++q) {
        if (!(scMask & (1 << q))) {
          const double r = minv + (double)cf[q] - u_i - v[q];
          if (r < shortest[q]) {
            shortest[q] = r;
            sh_path[q * 64 + lane] = i;        // own permuted slot for j=lane*8+q
          }
          if (shortest[q] < best) { best = shortest[q]; bj = lane * 8 + q; brow = rc[q]; }
        }
      }
#pragma unroll
      for (int off = 1; off < 64; off <<= 1) {
        const double ov = __shfl_xor(best, off);
        const int oj = __shfl_xor(bj, off);
        const int orow = __shfl_xor(brow, off);
        if (lex_less(ov, oj, best, bj)) { best = ov; bj = oj; brow = orow; }
      }
      // force wave-uniform pop decision
      best = __shfl(best, 0); bj = __shfl(bj, 0); brow = __shfl(brow, 0);
      minv = best;
      if ((bj >> 3) == lane) scMask |= 1 << (bj & 7);  // freeze popped column
      if (brow < 0) { sink = bj; break; }
      if (lane == 0) { sh_enter[brow] = best; sh_SRlist[nSR] = brow; }
      nSR++;  // wave-uniform
      i = brow;
    }

    __syncthreads();  // fence: sh_path / sh_enter / sh_SRlist visible

    for (int t = lane; t < nSR; t += 64) {
      const int r = sh_SRlist[t];
      sh_u[r] += minv - sh_enter[r];
    }
    if (lane == 0) sh_u[cur_row] = minv;       // free row: u starts at 0
#pragma unroll
    for (int q = 0; q < 8; ++q)
      if (scMask & (1 << q)) v[q] -= minv - shortest[q];

    if (lane == 0) {
      int j = sink;
      while (true) {
        const int ii = sh_path[(j & 7) * 64 + (j >> 3)];
        sh_row4col[j] = ii;
        const int tmp = sh_col4row[ii];
        sh_col4row[ii] = j;
        j = tmp;
        if (ii == cur_row) break;
      }
    }
    __syncthreads();  // fence: row4col / col4row / u visible
#pragma unroll
    for (int q = 0; q < 8; ++q) rc[q] = sh_row4col[lane * 8 + q];
  }

#pragma unroll
  for (int q = 0; q < 8; ++q) {
    const int r = q * 64 + lane;
    const int c4 = sh_col4row[r];
    if (c4 >= 0) outp[(size_t)r * NN + c4] = 1.0f;   // defensive: never OOB
  }
}

extern "C" void kernel_launch(void* const* d_in, const int* in_sizes, int n_in,
                              void* d_out, int out_size, void* d_ws, size_t ws_size,
                              hipStream_t stream) {
  const float* un1 = (const float*)d_in[0];
  const float* un2 = (const float*)d_in[1];
  const float* un3 = (const float*)d_in[2];
  float* out = (float*)d_out;

  float* cost = (float*)d_ws;                       // 3 * 512 * 512 floats
  float* scales = cost + (size_t)3 * NN * NN;       // 3 * 512 floats

  hipMemsetAsync(d_out, 0, (size_t)out_size * sizeof(float), stream);

  norm_kernel<<<dim3(NN, 3), 256, 0, stream>>>(un1, un2, un3, scales);
  cost_gemm_kernel<<<dim3(NN / 64, NN / 64, 3), 256, 0, stream>>>(un1, un2, un3, scales, cost);
  lap_kernel<<<3, 64, 0, stream>>>(cost, out);
}